// Round 2
// baseline (291.488 us; speedup 1.0000x reference)
//
#include <hip/hip_runtime.h>
#include <math.h>

// Router: B=4, S=8192, D=1024, E=64, TOP_K=2 (all fp32)
// logits[t,e] = sum_d h[t,d]*w[e,d]; softmax over e; top-2 (vals+idx); renorm.
// Output layout (fp32, concatenated flat):
//   [0,       65536)   top_k_probs   [4,8192,2]
//   [65536,   131072)  selected_experts (as float) [4,8192,2]
//   [131072,  2228224) router_logits [4,8192,64]
//
// R1 design: 4 tokens x 4 experts per lane (acc[4][4]), K-chunks of 8 floats,
// explicit register double-buffering (A0/W0 <-> A1/W1, all statically indexed)
// so each chunk's 16 float4 loads are in flight under the previous chunk's
// 128 FMAs. 512 blocks x 256 threads = 2 waves/SIMD; latency hidden by ILP.

static constexpr int TOKENS = 32768;
static constexpr int DDIM   = 1024;
static constexpr int NEXP   = 64;
static constexpr size_t OFF_EXP = 65536;
static constexpr size_t OFF_LOG = 131072;

#define LOAD_CHUNK(Abuf, Wbuf, kk)                                         \
  {                                                                        \
    _Pragma("unroll")                                                      \
    for (int t = 0; t < 4; ++t) {                                          \
      Abuf[t][0] = *reinterpret_cast<const float4*>(ha[t] + (kk));         \
      Abuf[t][1] = *reinterpret_cast<const float4*>(ha[t] + (kk) + 4);     \
    }                                                                      \
    _Pragma("unroll")                                                      \
    for (int e = 0; e < 4; ++e) {                                          \
      Wbuf[e][0] = *reinterpret_cast<const float4*>(wa[e] + (kk));         \
      Wbuf[e][1] = *reinterpret_cast<const float4*>(wa[e] + (kk) + 4);     \
    }                                                                      \
  }

// chunk-local partial (8-FMA chain) then one add into acc: keeps rounding
// error at the level that already passed validation.
#define FMA_CHUNK(Abuf, Wbuf)                                              \
  {                                                                        \
    _Pragma("unroll")                                                      \
    for (int t = 0; t < 4; ++t) {                                          \
      _Pragma("unroll")                                                    \
      for (int e = 0; e < 4; ++e) {                                        \
        float c;                                                           \
        c = Abuf[t][0].x * Wbuf[e][0].x;                                   \
        c = fmaf(Abuf[t][0].y, Wbuf[e][0].y, c);                           \
        c = fmaf(Abuf[t][0].z, Wbuf[e][0].z, c);                           \
        c = fmaf(Abuf[t][0].w, Wbuf[e][0].w, c);                           \
        c = fmaf(Abuf[t][1].x, Wbuf[e][1].x, c);                           \
        c = fmaf(Abuf[t][1].y, Wbuf[e][1].y, c);                           \
        c = fmaf(Abuf[t][1].z, Wbuf[e][1].z, c);                           \
        c = fmaf(Abuf[t][1].w, Wbuf[e][1].w, c);                           \
        acc[t][e] += c;                                                    \
      }                                                                    \
    }                                                                      \
  }

__global__ __launch_bounds__(256, 2)
void router_kernel(const float* __restrict__ h,
                   const float* __restrict__ w,
                   float* __restrict__ out) {
    const int tid  = threadIdx.x;
    const int lane = tid & 63;
    const int wv   = tid >> 6;
    const int tg   = lane & 3;    // token group: 4 groups of 4 tokens
    const int eg   = lane >> 2;   // expert group: 16 groups of 4 experts
    const int token0 = blockIdx.x * 64 + wv * 16 + tg * 4;
    const int e0     = eg * 4;

    const float* ha[4];
    const float* wa[4];
#pragma unroll
    for (int t = 0; t < 4; ++t) ha[t] = h + (size_t)(token0 + t) * DDIM;
#pragma unroll
    for (int e = 0; e < 4; ++e) wa[e] = w + (size_t)(e0 + e) * DDIM;

    float acc[4][4];
#pragma unroll
    for (int t = 0; t < 4; ++t)
#pragma unroll
        for (int e = 0; e < 4; ++e) acc[t][e] = 0.0f;

    float4 A0[4][2], W0[4][2], A1[4][2], W1[4][2];

    LOAD_CHUNK(A0, W0, 0);
    for (int k0 = 0; k0 < DDIM - 16; k0 += 16) {
        LOAD_CHUNK(A1, W1, k0 + 8);    // next chunk's loads in flight...
        FMA_CHUNK(A0, W0);             // ...under current chunk's FMAs
        LOAD_CHUNK(A0, W0, k0 + 16);
        FMA_CHUNK(A1, W1);
    }
    // A0/W0 hold chunk DDIM-16 here
    LOAD_CHUNK(A1, W1, DDIM - 8);
    FMA_CHUNK(A0, W0);
    FMA_CHUNK(A1, W1);

    // ---- write logits: per t, 16 eg-lanes cover a contiguous 256 B row ----
#pragma unroll
    for (int t = 0; t < 4; ++t) {
        float4 v = make_float4(acc[t][0], acc[t][1], acc[t][2], acc[t][3]);
        *reinterpret_cast<float4*>(out + OFF_LOG + (size_t)(token0 + t) * NEXP + e0) = v;
    }

    // ---- per-token softmax + top-2 across the 16 eg-lanes (xor 4..32) ----
#pragma unroll
    for (int t = 0; t < 4; ++t) {
        float m = fmaxf(fmaxf(acc[t][0], acc[t][1]),
                        fmaxf(acc[t][2], acc[t][3]));
#pragma unroll
        for (int d = 4; d <= 32; d <<= 1) m = fmaxf(m, __shfl_xor(m, d, 64));

        float p[4];
        float s = 0.0f;
#pragma unroll
        for (int e = 0; e < 4; ++e) { p[e] = expf(acc[t][e] - m); s += p[e]; }
#pragma unroll
        for (int d = 4; d <= 32; d <<= 1) s += __shfl_xor(s, d, 64);

        // local top-2 (strict '>' => lower index wins ties)
        float v1 = -INFINITY, v2 = -INFINITY;
        int   i1 = NEXP,      i2 = NEXP;
#pragma unroll
        for (int e = 0; e < 4; ++e) {
            float v = p[e];
            int   ei = e0 + e;
            if (v > v1)      { v2 = v1; i2 = i1; v1 = v; i1 = ei; }
            else if (v > v2) { v2 = v;  i2 = ei; }
        }

        // merge top-2 across the 16 expert-group lanes
#pragma unroll
        for (int d = 4; d <= 32; d <<= 1) {
            float ov1 = __shfl_xor(v1, d, 64);
            float ov2 = __shfl_xor(v2, d, 64);
            int   oi1 = __shfl_xor(i1, d, 64);
            int   oi2 = __shfl_xor(i2, d, 64);
            bool ofirst = (ov1 > v1) || (ov1 == v1 && oi1 < i1);
            float n1, n2; int ni1, ni2;
            if (ofirst) {
                n1 = ov1; ni1 = oi1;
                bool sec = (v1 > ov2) || (v1 == ov2 && i1 < oi2);
                n2 = sec ? v1 : ov2; ni2 = sec ? i1 : oi2;
            } else {
                n1 = v1; ni1 = i1;
                bool sec = (ov1 > v2) || (ov1 == v2 && oi1 < i2);
                n2 = sec ? ov1 : v2; ni2 = sec ? oi1 : i2;
            }
            v1 = n1; i1 = ni1; v2 = n2; i2 = ni2;
        }

        if (eg == 0) {
            float t1 = v1 / s;
            float t2 = v2 / s;
            float dn = t1 + t2 + 1e-8f;
            float2 pr; pr.x = t1 / dn; pr.y = t2 / dn;
            *reinterpret_cast<float2*>(out + (size_t)(token0 + t) * 2) = pr;
            float2 ex; ex.x = (float)i1; ex.y = (float)i2;
            *reinterpret_cast<float2*>(out + OFF_EXP + (size_t)(token0 + t) * 2) = ex;
        }
    }
}

extern "C" void kernel_launch(void* const* d_in, const int* in_sizes, int n_in,
                              void* d_out, int out_size, void* d_ws, size_t ws_size,
                              hipStream_t stream) {
    const float* h = (const float*)d_in[0];
    const float* w = (const float*)d_in[1];
    float* out = (float*)d_out;
    dim3 grid(TOKENS / 64);
    dim3 block(256);
    hipLaunchKernelGGL(router_kernel, grid, block, 0, stream, h, w, out);
}

// Round 3
// 191.270 us; speedup vs baseline: 1.5240x; 1.5240x over previous
//
#include <hip/hip_runtime.h>
#include <math.h>

// Router: B=4, S=8192, D=1024, E=64, TOP_K=2 (all fp32)
// Output layout (fp32, concatenated flat):
//   [0,       65536)   top_k_probs   [4,8192,2]
//   [65536,   131072)  selected_experts (as float) [4,8192,2]
//   [131072,  2228224) router_logits [4,8192,64]
//
// R2 design: K split across lanes. lane = kslot*16 + eg.
//   kslot = lane>>4 in [0,4): covers k = kslot*4..+3 (mod 16)
//   eg    = lane&15 in [0,16): covers experts eg*4..eg*4+3
// Each lane: acc[8 tokens][4 experts], direct FMA over its 256-element K slice.
// W load instr: 16 experts x 64B contiguous = 16 FULL cache lines (was 25% util).
// A load instr: one 64B line, 16-way broadcast.
// End: 2x shfl_xor (16,32) sums kslot partials; softmax/top-2 merge over eg.
// 1024 blocks x 256 thr, ~3 waves/SIMD: TLP hides latency (R1's compiler-
// collapsed register dbuf showed ILP alone is fragile here).

static constexpr int TOKENS = 32768;
static constexpr int DDIM   = 1024;
static constexpr int NEXP   = 64;
static constexpr size_t OFF_EXP = 65536;
static constexpr size_t OFF_LOG = 131072;

__global__ __launch_bounds__(256, 3)
void router_kernel(const float* __restrict__ h,
                   const float* __restrict__ w,
                   float* __restrict__ out) {
    const int tid   = threadIdx.x;
    const int lane  = tid & 63;
    const int wv    = tid >> 6;
    const int eg    = lane & 15;   // expert group: experts eg*4..+3
    const int kslot = lane >> 4;   // k-slice: k = kslot*4..+3 (mod 16)
    const int token0 = blockIdx.x * 32 + wv * 8;

    const float* __restrict__ hp = h + (size_t)token0 * DDIM + kslot * 4;
    const float* __restrict__ wp = w + (size_t)(eg * 4) * DDIM + kslot * 4;

    float acc[8][4] = {};

#pragma unroll 2
    for (int k0 = 0; k0 < DDIM; k0 += 16) {
        float4 A[8];
#pragma unroll
        for (int t = 0; t < 8; ++t)
            A[t] = *reinterpret_cast<const float4*>(hp + (size_t)t * DDIM + k0);
        float4 W[4];
#pragma unroll
        for (int j = 0; j < 4; ++j)
            W[j] = *reinterpret_cast<const float4*>(wp + (size_t)j * DDIM + k0);

#pragma unroll
        for (int t = 0; t < 8; ++t)
#pragma unroll
            for (int j = 0; j < 4; ++j) {
                acc[t][j] = fmaf(A[t].x, W[j].x, acc[t][j]);
                acc[t][j] = fmaf(A[t].y, W[j].y, acc[t][j]);
                acc[t][j] = fmaf(A[t].z, W[j].z, acc[t][j]);
                acc[t][j] = fmaf(A[t].w, W[j].w, acc[t][j]);
            }
    }

    // ---- sum the 4 kslot partials (all lanes end with full logits) ----
#pragma unroll
    for (int t = 0; t < 8; ++t)
#pragma unroll
        for (int j = 0; j < 4; ++j) {
            acc[t][j] += __shfl_xor(acc[t][j], 16, 64);
            acc[t][j] += __shfl_xor(acc[t][j], 32, 64);
        }

    // ---- write logits: kslot==0 lanes, 16 lanes x 16B contiguous/token ----
    if (kslot == 0) {
#pragma unroll
        for (int t = 0; t < 8; ++t) {
            float4 v = make_float4(acc[t][0], acc[t][1], acc[t][2], acc[t][3]);
            *reinterpret_cast<float4*>(
                out + OFF_LOG + (size_t)(token0 + t) * NEXP + eg * 4) = v;
        }
    }

    // ---- per-token softmax + top-2 (merge across eg via xor 1,2,4,8) ----
#pragma unroll
    for (int t = 0; t < 8; ++t) {
        float m = fmaxf(fmaxf(acc[t][0], acc[t][1]),
                        fmaxf(acc[t][2], acc[t][3]));
#pragma unroll
        for (int d = 1; d <= 8; d <<= 1) m = fmaxf(m, __shfl_xor(m, d, 64));

        float p[4];
        float s = 0.0f;
#pragma unroll
        for (int j = 0; j < 4; ++j) { p[j] = expf(acc[t][j] - m); s += p[j]; }
#pragma unroll
        for (int d = 1; d <= 8; d <<= 1) s += __shfl_xor(s, d, 64);

        // local top-2 (strict '>' => lower index wins ties)
        float v1 = -INFINITY, v2 = -INFINITY;
        int   i1 = NEXP,      i2 = NEXP;
#pragma unroll
        for (int j = 0; j < 4; ++j) {
            float v = p[j];
            int   ei = eg * 4 + j;
            if (v > v1)      { v2 = v1; i2 = i1; v1 = v; i1 = ei; }
            else if (v > v2) { v2 = v;  i2 = ei; }
        }

        // merge across the 16 eg lanes
#pragma unroll
        for (int d = 1; d <= 8; d <<= 1) {
            float ov1 = __shfl_xor(v1, d, 64);
            float ov2 = __shfl_xor(v2, d, 64);
            int   oi1 = __shfl_xor(i1, d, 64);
            int   oi2 = __shfl_xor(i2, d, 64);
            bool ofirst = (ov1 > v1) || (ov1 == v1 && oi1 < i1);
            float n1, n2; int ni1, ni2;
            if (ofirst) {
                n1 = ov1; ni1 = oi1;
                bool sec = (v1 > ov2) || (v1 == ov2 && i1 < oi2);
                n2 = sec ? v1 : ov2; ni2 = sec ? i1 : oi2;
            } else {
                n1 = v1; ni1 = i1;
                bool sec = (ov1 > v2) || (ov1 == v2 && oi1 < i2);
                n2 = sec ? ov1 : v2; ni2 = sec ? oi1 : i2;
            }
            v1 = n1; i1 = ni1; v2 = n2; i2 = ni2;
        }

        if (lane == 0) {
            float t1 = v1 / s;
            float t2 = v2 / s;
            float dn = t1 + t2 + 1e-8f;
            float2 pr; pr.x = t1 / dn; pr.y = t2 / dn;
            *reinterpret_cast<float2*>(out + (size_t)(token0 + t) * 2) = pr;
            float2 ex; ex.x = (float)i1; ex.y = (float)i2;
            *reinterpret_cast<float2*>(out + OFF_EXP + (size_t)(token0 + t) * 2) = ex;
        }
    }
}

extern "C" void kernel_launch(void* const* d_in, const int* in_sizes, int n_in,
                              void* d_out, int out_size, void* d_ws, size_t ws_size,
                              hipStream_t stream) {
    const float* h = (const float*)d_in[0];
    const float* w = (const float*)d_in[1];
    float* out = (float*)d_out;
    dim3 grid(TOKENS / 32);
    dim3 block(256);
    hipLaunchKernelGGL(router_kernel, grid, block, 0, stream, h, w, out);
}

// Round 5
// 65.451 us; speedup vs baseline: 4.4535x; 2.9224x over previous
//
#include <hip/hip_runtime.h>
#include <math.h>

// Router: B=4, S=8192, D=1024, E=64, TOP_K=2 (all fp32)
// Output layout (fp32, concatenated flat):
//   [0,       65536)   top_k_probs   [4,8192,2]
//   [65536,   131072)  selected_experts (as float) [4,8192,2]
//   [131072,  2228224) router_logits [4,8192,64]
//
// R5: fp32-EXACT 3-level bf16 split MFMA.
//   fp32 mantissa (24 bits) == 3 x 8-bit bf16 chunks, so successive
//   truncation a = a1+a2+a3 is EXACT (bf16 exponent range == fp32).
//   logits = sum of 6 MFMA terms: a1w1 + a1w2 + a2w1 + a2w2 + a1w3 + a3w1
//   (dropped terms are ~2^-24 relative -> ~1e-7 coherent). Remaining error
//   = fp32 accumulation rounding (~1.5e-6), SAME class as the R2 fp32-VALU
//   kernel that passed index validation. R4's 3-term truncation split
//   (~1e-4..1e-3 error) flipped near-tie top-2 indices; this fixes that.
//   Layout/permutation machinery is unchanged from R4 (validated: probs
//   passed, so fragment mapping is right).
//   Wave = 32 tokens (2 M-tiles) x 64 experts x K-half(512): the 12 W-frag
//   loads per chunk are shared across both M-tiles (halves W' L2 traffic).
//   512 blocks x 256 thr = 2048 waves = 2/SIMD.

typedef __attribute__((ext_vector_type(8))) short bf16x8;
typedef __attribute__((ext_vector_type(4))) float f32x4;

static constexpr int TOKENS = 32768;
static constexpr int DDIM   = 1024;
static constexpr int NEXP   = 64;
static constexpr size_t OFF_EXP = 65536;
static constexpr size_t OFF_LOG = 131072;

// ---- W 3-level split + fragment-order permute ----
// element (e,k): tile n=e>>4, chunk c=k>>5, lane=(e&15)+16*((k&31)>>3), j=k&7
// dst (shorts) = ((c*4+n)*64 + lane)*8 + j   (bijection, validated in R4)
__global__ void w_split3_kernel(const float* __restrict__ w,
                                short* __restrict__ w1,
                                short* __restrict__ w2,
                                short* __restrict__ w3) {
    int idx = blockIdx.x * blockDim.x + threadIdx.x;
    for (int i = idx; i < NEXP * DDIM; i += gridDim.x * blockDim.x) {
        int e = i >> 10, k = i & 1023;
        float f = w[i];
        unsigned u1 = __float_as_uint(f);
        float f1 = __uint_as_float(u1 & 0xffff0000u);
        float r1 = f - f1;                       // exact (trailing bits)
        unsigned u2 = __float_as_uint(r1);
        float f2 = __uint_as_float(u2 & 0xffff0000u);
        float r2 = r1 - f2;                      // exact, <= 8 sig bits left
        unsigned u3 = __float_as_uint(r2);
        int n = e >> 4, c = k >> 5;
        int lane = (e & 15) + ((k & 31) >> 3) * 16;
        int j = k & 7;
        size_t dst = ((size_t)(c * 4 + n) * 64 + lane) * 8 + j;
        w1[dst] = (short)(u1 >> 16);
        w2[dst] = (short)(u2 >> 16);
        w3[dst] = (short)(u3 >> 16);
    }
}

__device__ inline void split8(float4 a, float4 b,
                              bf16x8& o1, bf16x8& o2, bf16x8& o3) {
    float f[8] = {a.x, a.y, a.z, a.w, b.x, b.y, b.z, b.w};
#pragma unroll
    for (int j = 0; j < 8; ++j) {
        unsigned u1 = __float_as_uint(f[j]);
        float f1 = __uint_as_float(u1 & 0xffff0000u);
        float r1 = f[j] - f1;
        unsigned u2 = __float_as_uint(r1);
        float f2 = __uint_as_float(u2 & 0xffff0000u);
        float r2 = r1 - f2;
        o1[j] = (short)(u1 >> 16);
        o2[j] = (short)(u2 >> 16);
        o3[j] = (short)(__float_as_uint(r2) >> 16);
    }
}

__global__ __launch_bounds__(256, 2)
void router_mfma_kernel(const float* __restrict__ h,
                        const short* __restrict__ w1,
                        const short* __restrict__ w2,
                        const short* __restrict__ w3,
                        float* __restrict__ out) {
    __shared__ float lds[2][64][33];   // [mgroup][lane][32 acc vals], pad 33
    const int tid   = threadIdx.x;
    const int lane  = tid & 63;
    const int wv    = tid >> 6;
    const int khalf = wv & 1;      // K half (0: k<512, 1: k>=512)
    const int mg    = wv >> 1;     // token group of 32 within block
    const int token0 = blockIdx.x * 64 + mg * 32;
    const int arow  = lane & 15;   // A-frag row (token offset within tile)
    const int ks    = lane >> 4;   // k slice within chunk

    const float* ap0 = h + (size_t)(token0 + arow) * DDIM + khalf * 512 + ks * 8;
    const float* ap1 = ap0 + (size_t)16 * DDIM;

    f32x4 acc[2][4];
#pragma unroll
    for (int m = 0; m < 2; ++m)
#pragma unroll
        for (int n = 0; n < 4; ++n)
#pragma unroll
            for (int r = 0; r < 4; ++r) acc[m][n][r] = 0.0f;

#pragma unroll 2
    for (int cc = 0; cc < 16; ++cc) {
        const int c = khalf * 16 + cc;   // global K-chunk index

        float4 a00 = *reinterpret_cast<const float4*>(ap0 + cc * 32);
        float4 a01 = *reinterpret_cast<const float4*>(ap0 + cc * 32 + 4);
        float4 a10 = *reinterpret_cast<const float4*>(ap1 + cc * 32);
        float4 a11 = *reinterpret_cast<const float4*>(ap1 + cc * 32 + 4);

        bf16x8 W1[4], W2[4], W3[4];
#pragma unroll
        for (int n = 0; n < 4; ++n) {
            size_t off = (size_t)(c * 4 + n) * 512 + lane * 8;
            W1[n] = *reinterpret_cast<const bf16x8*>(w1 + off);
            W2[n] = *reinterpret_cast<const bf16x8*>(w2 + off);
            W3[n] = *reinterpret_cast<const bf16x8*>(w3 + off);
        }

        bf16x8 A1[2], A2[2], A3[2];
        split8(a00, a01, A1[0], A2[0], A3[0]);
        split8(a10, a11, A1[1], A2[1], A3[1]);

#pragma unroll
        for (int m = 0; m < 2; ++m)
#pragma unroll
            for (int n = 0; n < 4; ++n) {
                f32x4 t = acc[m][n];
                t = __builtin_amdgcn_mfma_f32_16x16x32_bf16(A3[m], W1[n], t, 0, 0, 0);
                t = __builtin_amdgcn_mfma_f32_16x16x32_bf16(A1[m], W3[n], t, 0, 0, 0);
                t = __builtin_amdgcn_mfma_f32_16x16x32_bf16(A2[m], W2[n], t, 0, 0, 0);
                t = __builtin_amdgcn_mfma_f32_16x16x32_bf16(A2[m], W1[n], t, 0, 0, 0);
                t = __builtin_amdgcn_mfma_f32_16x16x32_bf16(A1[m], W2[n], t, 0, 0, 0);
                t = __builtin_amdgcn_mfma_f32_16x16x32_bf16(A1[m], W1[n], t, 0, 0, 0);
                acc[m][n] = t;
            }
    }

    // ---- combine K-halves through LDS ----
    if (khalf == 1) {
#pragma unroll
        for (int m = 0; m < 2; ++m)
#pragma unroll
            for (int n = 0; n < 4; ++n)
#pragma unroll
                for (int r = 0; r < 4; ++r)
                    lds[mg][lane][m * 16 + n * 4 + r] = acc[m][n][r];
    }
    __syncthreads();
    if (khalf != 0) return;

#pragma unroll
    for (int m = 0; m < 2; ++m)
#pragma unroll
        for (int n = 0; n < 4; ++n)
#pragma unroll
            for (int r = 0; r < 4; ++r)
                acc[m][n][r] += lds[mg][lane][m * 16 + n * 4 + r];

    const int rbase = (lane >> 4) * 4;   // C/D row group (token offset)
    const int col   = lane & 15;         // C/D col (expert within tile)

    // ---- logits ----
#pragma unroll
    for (int m = 0; m < 2; ++m)
#pragma unroll
        for (int n = 0; n < 4; ++n)
#pragma unroll
            for (int r = 0; r < 4; ++r)
                out[OFF_LOG + (size_t)(token0 + m * 16 + rbase + r) * NEXP
                    + n * 16 + col] = acc[m][n][r];

    // ---- softmax + top-2 per token (16-lane groups, xor 1,2,4,8) ----
#pragma unroll
    for (int m = 0; m < 2; ++m)
#pragma unroll
    for (int r = 0; r < 4; ++r) {
        const int token = token0 + m * 16 + rbase + r;
        float mx = fmaxf(fmaxf(acc[m][0][r], acc[m][1][r]),
                         fmaxf(acc[m][2][r], acc[m][3][r]));
#pragma unroll
        for (int d = 1; d <= 8; d <<= 1) mx = fmaxf(mx, __shfl_xor(mx, d, 64));

        float p[4];
        float s = 0.0f;
#pragma unroll
        for (int n = 0; n < 4; ++n) { p[n] = expf(acc[m][n][r] - mx); s += p[n]; }
#pragma unroll
        for (int d = 1; d <= 8; d <<= 1) s += __shfl_xor(s, d, 64);

        // local top-2 over n (expert = n*16 + col, ascending; '>' keeps lower)
        float v1 = -INFINITY, v2 = -INFINITY;
        int   i1 = NEXP,      i2 = NEXP;
#pragma unroll
        for (int n = 0; n < 4; ++n) {
            float v = p[n];
            int   ei = n * 16 + col;
            if (v > v1)      { v2 = v1; i2 = i1; v1 = v; i1 = ei; }
            else if (v > v2) { v2 = v;  i2 = ei; }
        }

        // merge across the 16 lanes of the group
#pragma unroll
        for (int d = 1; d <= 8; d <<= 1) {
            float ov1 = __shfl_xor(v1, d, 64);
            float ov2 = __shfl_xor(v2, d, 64);
            int   oi1 = __shfl_xor(i1, d, 64);
            int   oi2 = __shfl_xor(i2, d, 64);
            bool ofirst = (ov1 > v1) || (ov1 == v1 && oi1 < i1);
            float n1, n2; int ni1, ni2;
            if (ofirst) {
                n1 = ov1; ni1 = oi1;
                bool sec = (v1 > ov2) || (v1 == ov2 && i1 < oi2);
                n2 = sec ? v1 : ov2; ni2 = sec ? i1 : oi2;
            } else {
                n1 = v1; ni1 = i1;
                bool sec = (ov1 > v2) || (ov1 == v2 && oi1 < i2);
                n2 = sec ? ov1 : v2; ni2 = sec ? oi1 : i2;
            }
            v1 = n1; i1 = ni1; v2 = n2; i2 = ni2;
        }

        if (col == 0) {
            float t1 = v1 / s;
            float t2 = v2 / s;
            float dn = t1 + t2 + 1e-8f;
            float2 pr; pr.x = t1 / dn; pr.y = t2 / dn;
            *reinterpret_cast<float2*>(out + (size_t)token * 2) = pr;
            float2 ex; ex.x = (float)i1; ex.y = (float)i2;
            *reinterpret_cast<float2*>(out + OFF_EXP + (size_t)token * 2) = ex;
        }
    }
}

extern "C" void kernel_launch(void* const* d_in, const int* in_sizes, int n_in,
                              void* d_out, int out_size, void* d_ws, size_t ws_size,
                              hipStream_t stream) {
    const float* h = (const float*)d_in[0];
    const float* w = (const float*)d_in[1];
    float* out = (float*)d_out;
    // d_ws: W1 | W2 | W3, each 65536 shorts = 384 KiB total
    short* w1 = (short*)d_ws;
    short* w2 = w1 + (size_t)NEXP * DDIM;
    short* w3 = w2 + (size_t)NEXP * DDIM;
    hipLaunchKernelGGL(w_split3_kernel, dim3(64), dim3(256), 0, stream, w, w1, w2, w3);
    hipLaunchKernelGGL(router_mfma_kernel, dim3(TOKENS / 64), dim3(256), 0, stream,
                       h, w1, w2, w3, out);
}

// Round 6
// 43.635 us; speedup vs baseline: 6.6801x; 1.5000x over previous
//
#include <hip/hip_runtime.h>
#include <math.h>

// Router: B=4, S=8192, D=1024, E=64, TOP_K=2 (all fp32)
// Output layout (fp32, concatenated flat):
//   [0,       65536)   top_k_probs   [4,8192,2]
//   [65536,   131072)  selected_experts (as float) [4,8192,2]
//   [131072,  2228224) router_logits [4,8192,64]
//
// R6: R5's fp32-exact 3-level bf16-split MFMA (validated), restructured for
// latency: W' chunk-staged in LDS via global_load_lds(16B), double-buffered,
// one barrier per chunk (T3 minimal 2-phase); A prefetched 1 chunk ahead in
// regs. Block = 512 thr = 8 waves (4 mg x 2 khalf), 64 tokens/block; grid
// 512 -> 4096 waves = 4/SIMD (2 blocks/CU, 48 KB LDS each).
// W' L2 traffic drops 4x (per-block instead of per-wave-pair).

typedef __attribute__((ext_vector_type(8))) short bf16x8;
typedef __attribute__((ext_vector_type(4))) float f32x4;

static constexpr int TOKENS = 32768;
static constexpr int DDIM   = 1024;
static constexpr int NEXP   = 64;
static constexpr size_t OFF_EXP = 65536;
static constexpr size_t OFF_LOG = 131072;

// ---- W 3-level split + fragment-order permute (validated R4/R5) ----
// element (e,k): tile n=e>>4, chunk c=k>>5, lane=(e&15)+16*((k&31)>>3), j=k&7
// dst (shorts) = ((c*4+n)*64 + lane)*8 + j
__global__ void w_split3_kernel(const float* __restrict__ w,
                                short* __restrict__ w1,
                                short* __restrict__ w2,
                                short* __restrict__ w3) {
    int idx = blockIdx.x * blockDim.x + threadIdx.x;
    for (int i = idx; i < NEXP * DDIM; i += gridDim.x * blockDim.x) {
        int e = i >> 10, k = i & 1023;
        float f = w[i];
        unsigned u1 = __float_as_uint(f);
        float f1 = __uint_as_float(u1 & 0xffff0000u);
        float r1 = f - f1;
        unsigned u2 = __float_as_uint(r1);
        float f2 = __uint_as_float(u2 & 0xffff0000u);
        float r2 = r1 - f2;
        unsigned u3 = __float_as_uint(r2);
        int n = e >> 4, c = k >> 5;
        int lane = (e & 15) + ((k & 31) >> 3) * 16;
        int j = k & 7;
        size_t dst = ((size_t)(c * 4 + n) * 64 + lane) * 8 + j;
        w1[dst] = (short)(u1 >> 16);
        w2[dst] = (short)(u2 >> 16);
        w3[dst] = (short)(u3 >> 16);
    }
}

__device__ inline void split8(float4 a, float4 b,
                              bf16x8& o1, bf16x8& o2, bf16x8& o3) {
    float f[8] = {a.x, a.y, a.z, a.w, b.x, b.y, b.z, b.w};
#pragma unroll
    for (int j = 0; j < 8; ++j) {
        unsigned u1 = __float_as_uint(f[j]);
        float f1 = __uint_as_float(u1 & 0xffff0000u);
        float r1 = f[j] - f1;
        unsigned u2 = __float_as_uint(r1);
        float f2 = __uint_as_float(u2 & 0xffff0000u);
        float r2 = r1 - f2;
        o1[j] = (short)(u1 >> 16);
        o2[j] = (short)(u2 >> 16);
        o3[j] = (short)(__float_as_uint(r2) >> 16);
    }
}

// global->LDS DMA, 16B/lane. LDS dest = wave-uniform base + lane*16 (HW);
// global src is per-lane. Integer casts: as3 = low 32 bits of generic LDS addr.
typedef const __attribute__((address_space(1))) unsigned int* gas1_t;
typedef __attribute__((address_space(3))) unsigned int* las3_t;
__device__ inline void stage16(const void* g, void* l) {
    __builtin_amdgcn_global_load_lds((gas1_t)(uintptr_t)g,
                                     (las3_t)(uintptr_t)l, 16, 0, 0);
}

__global__ __launch_bounds__(512, 4)
void router_mfma_kernel(const float* __restrict__ h,
                        const short* __restrict__ w1,
                        const short* __restrict__ w2,
                        const short* __restrict__ w3,
                        float* __restrict__ out) {
    // [0,24576): buf0, [24576,49152): buf1. Each buf: [khalf][arr][n] x 1KB.
    // Combine phase overlays [0,17408) after the main loop.
    __shared__ alignas(16) char smem[49152];
    const int tid   = threadIdx.x;
    const int lane  = tid & 63;
    const int wv    = tid >> 6;     // 0..7
    const int khalf = wv & 1;       // K half (0: k<512, 1: k>=512)
    const int mg    = wv >> 1;      // M-tile group 0..3
    const int token0 = blockIdx.x * 64 + mg * 16;
    const int arow  = lane & 15;    // A-frag row (token within tile)
    const int ks    = lane >> 4;    // k slice within chunk

    const float* ap = h + (size_t)(token0 + arow) * DDIM + khalf * 512 + ks * 8;

    // staging assignment: seg = wv*3+i; seg = (a*4+n)*2 + kh
    const short* warr[3] = {w1, w2, w3};
    const char* gsrc[3];
    int ldso[3];
#pragma unroll
    for (int i = 0; i < 3; ++i) {
        int seg = wv * 3 + i;
        int kh = seg & 1;
        int an = seg >> 1;          // 0..11
        int a = an >> 2, n = an & 3;
        // global chunk c = kh*16 + cc; byte src = ((c*4+n)*1024) + lane*16
        //   = (kh*64 + n)*1024 + cc*4096 + lane*16
        gsrc[i] = (const char*)warr[a] + (size_t)(kh * 64 + n) * 1024 + lane * 16;
        ldso[i] = (kh * 12 + a * 4 + n) * 1024;
    }

#define STAGE(bb, cc)                                                      \
    {                                                                      \
        _Pragma("unroll")                                                  \
        for (int i = 0; i < 3; ++i)                                        \
            stage16(gsrc[i] + (size_t)(cc) * 4096,                         \
                    smem + (bb) * 24576 + ldso[i]);                        \
    }

    f32x4 acc[4];
#pragma unroll
    for (int n = 0; n < 4; ++n)
#pragma unroll
        for (int r = 0; r < 4; ++r) acc[n][r] = 0.0f;

    float4 a0c = *reinterpret_cast<const float4*>(ap);
    float4 a1c = *reinterpret_cast<const float4*>(ap + 4);
    STAGE(0, 0);
    __syncthreads();

    float4 a0n, a1n;
#pragma unroll 2
    for (int t = 0; t < 16; ++t) {
        const int b = t & 1;
        if (t < 15) {
            STAGE(b ^ 1, t + 1);                       // DMA next W chunk
            a0n = *reinterpret_cast<const float4*>(ap + (t + 1) * 32);
            a1n = *reinterpret_cast<const float4*>(ap + (t + 1) * 32 + 4);
        }

        bf16x8 A1f, A2f, A3f;
        split8(a0c, a1c, A1f, A2f, A3f);

        const char* wb = smem + b * 24576 + khalf * 12288 + lane * 16;
#pragma unroll
        for (int n = 0; n < 4; ++n) {
            bf16x8 W1v = *reinterpret_cast<const bf16x8*>(wb + n * 1024);
            bf16x8 W2v = *reinterpret_cast<const bf16x8*>(wb + n * 1024 + 4096);
            bf16x8 W3v = *reinterpret_cast<const bf16x8*>(wb + n * 1024 + 8192);
            f32x4 t2 = acc[n];
            t2 = __builtin_amdgcn_mfma_f32_16x16x32_bf16(A3f, W1v, t2, 0, 0, 0);
            t2 = __builtin_amdgcn_mfma_f32_16x16x32_bf16(A1f, W3v, t2, 0, 0, 0);
            t2 = __builtin_amdgcn_mfma_f32_16x16x32_bf16(A2f, W2v, t2, 0, 0, 0);
            t2 = __builtin_amdgcn_mfma_f32_16x16x32_bf16(A2f, W1v, t2, 0, 0, 0);
            t2 = __builtin_amdgcn_mfma_f32_16x16x32_bf16(A1f, W2v, t2, 0, 0, 0);
            t2 = __builtin_amdgcn_mfma_f32_16x16x32_bf16(A1f, W1v, t2, 0, 0, 0);
            acc[n] = t2;
        }
        __syncthreads();   // drains DMA (vmcnt) + all reads of buf b done
        a0c = a0n; a1c = a1n;
    }

    // ---- combine K-halves through LDS (overlay region, stride 17 floats) ----
    if (khalf == 1) {
        float* c = (float*)smem + (size_t)(mg * 64 + lane) * 17;
#pragma unroll
        for (int n = 0; n < 4; ++n)
#pragma unroll
            for (int r = 0; r < 4; ++r) c[n * 4 + r] = acc[n][r];
    }
    __syncthreads();
    if (khalf != 0) return;

    {
        const float* c = (const float*)smem + (size_t)(mg * 64 + lane) * 17;
#pragma unroll
        for (int n = 0; n < 4; ++n)
#pragma unroll
            for (int r = 0; r < 4; ++r) acc[n][r] += c[n * 4 + r];
    }

    const int rbase = (lane >> 4) * 4;   // C/D row group (token offset)
    const int col   = lane & 15;         // C/D col (expert within tile)

    // ---- logits ----
#pragma unroll
    for (int n = 0; n < 4; ++n)
#pragma unroll
        for (int r = 0; r < 4; ++r)
            out[OFF_LOG + (size_t)(token0 + rbase + r) * NEXP + n * 16 + col]
                = acc[n][r];

    // ---- softmax + top-2 per token (16-lane groups, xor 1,2,4,8) ----
#pragma unroll
    for (int r = 0; r < 4; ++r) {
        const int token = token0 + rbase + r;
        float mx = fmaxf(fmaxf(acc[0][r], acc[1][r]),
                         fmaxf(acc[2][r], acc[3][r]));
#pragma unroll
        for (int d = 1; d <= 8; d <<= 1) mx = fmaxf(mx, __shfl_xor(mx, d, 64));

        float p[4];
        float s = 0.0f;
#pragma unroll
        for (int n = 0; n < 4; ++n) { p[n] = expf(acc[n][r] - mx); s += p[n]; }
#pragma unroll
        for (int d = 1; d <= 8; d <<= 1) s += __shfl_xor(s, d, 64);

        // local top-2 over n (expert = n*16 + col, ascending; '>' keeps lower)
        float v1 = -INFINITY, v2 = -INFINITY;
        int   i1 = NEXP,      i2 = NEXP;
#pragma unroll
        for (int n = 0; n < 4; ++n) {
            float v = p[n];
            int   ei = n * 16 + col;
            if (v > v1)      { v2 = v1; i2 = i1; v1 = v; i1 = ei; }
            else if (v > v2) { v2 = v;  i2 = ei; }
        }

        // merge across the 16 lanes of the group
#pragma unroll
        for (int d = 1; d <= 8; d <<= 1) {
            float ov1 = __shfl_xor(v1, d, 64);
            float ov2 = __shfl_xor(v2, d, 64);
            int   oi1 = __shfl_xor(i1, d, 64);
            int   oi2 = __shfl_xor(i2, d, 64);
            bool ofirst = (ov1 > v1) || (ov1 == v1 && oi1 < i1);
            float n1, n2; int ni1, ni2;
            if (ofirst) {
                n1 = ov1; ni1 = oi1;
                bool sec = (v1 > ov2) || (v1 == ov2 && i1 < oi2);
                n2 = sec ? v1 : ov2; ni2 = sec ? i1 : oi2;
            } else {
                n1 = v1; ni1 = i1;
                bool sec = (ov1 > v2) || (ov1 == v2 && oi1 < i2);
                n2 = sec ? ov1 : v2; ni2 = sec ? oi1 : i2;
            }
            v1 = n1; i1 = ni1; v2 = n2; i2 = ni2;
        }

        if (col == 0) {
            float t1 = v1 / s;
            float t2 = v2 / s;
            float dn = t1 + t2 + 1e-8f;
            float2 pr; pr.x = t1 / dn; pr.y = t2 / dn;
            *reinterpret_cast<float2*>(out + (size_t)token * 2) = pr;
            float2 ex; ex.x = (float)i1; ex.y = (float)i2;
            *reinterpret_cast<float2*>(out + OFF_EXP + (size_t)token * 2) = ex;
        }
    }
#undef STAGE
}

extern "C" void kernel_launch(void* const* d_in, const int* in_sizes, int n_in,
                              void* d_out, int out_size, void* d_ws, size_t ws_size,
                              hipStream_t stream) {
    const float* h = (const float*)d_in[0];
    const float* w = (const float*)d_in[1];
    float* out = (float*)d_out;
    // d_ws: W1 | W2 | W3, each 65536 shorts = 384 KiB total
    short* w1 = (short*)d_ws;
    short* w2 = w1 + (size_t)NEXP * DDIM;
    short* w3 = w2 + (size_t)NEXP * DDIM;
    hipLaunchKernelGGL(w_split3_kernel, dim3(128), dim3(256), 0, stream, w, w1, w2, w3);
    hipLaunchKernelGGL(router_mfma_kernel, dim3(TOKENS / 64), dim3(512), 0, stream,
                       h, w1, w2, w3, out);
}